// Round 7
// baseline (1169.174 us; speedup 1.0000x reference)
//
#include <hip/hip_runtime.h>

// GCN aggregation — bucketed partition + feature-sliced XCD-pinned gather.
//   out = diag(in_deg^-1/2) * A * diag(out_deg^-1/2) * concat(u_f, v_f)
//
// Pipeline:
//   init : gcurD[b]=gcurS[b]=b*BCAP
//   P1s  : partition src keys into 128-node buckets (LDS staged)
//   P2s  : per-bucket LDS histogram -> odeg
//   P1d  : partition edges by dst bucket, PACKED (d_local<<24|src) uint
//   cast : sliced bf16 table  tbl[slice][node][16] = bf16(node_f * rsqrt(odeg))
//   agg  : block=(bucket,slice); slice=bid%8 -> pinned XCD; 3.2MB slice table
//          L2-resident; LDS f32 accum (stride 17) + local in-degree + fused norm
//
// Fallback (small ws): round-5 slack-CSR random-atomic build + f32 gather.

#define DFEAT 128
#define SLACK 64
#define OVF2_CAP 65536
#define OVFD_CAP 65536
#define BSHIFT 7
#define BNODES 128
#define MAXBUK 1024         // supports nN <= 131072
#define BCAP 4096
#define CH 6144
#define NSLICE 8
#define SFEAT 16            // features per slice

// ---------------- init ----------------
__global__ void init_kernel(int* __restrict__ gcurD, int* __restrict__ gcurS,
                            int nbuk) {
    int b = blockIdx.x * blockDim.x + threadIdx.x;
    if (b < nbuk) { gcurD[b] = b * BCAP; gcurS[b] = b * BCAP; }
}

// ---------------- partition: (dst,src) pairs, packed flush ----------------
__global__ __launch_bounds__(256)
void partition_pairs_kernel(const int* __restrict__ dst,
                            const int* __restrict__ src,
                            int* __restrict__ gcur,
                            unsigned* __restrict__ part,   // packed uint
                            int2* __restrict__ ovf,
                            int* __restrict__ ovf_cnt,
                            int nE, int nbuk) {
    __shared__ int hist[MAXBUK];
    __shared__ int dlt[MAXBUK];
    __shared__ int wsum[4];
    __shared__ unsigned sk[CH];
    __shared__ unsigned sv[CH];

    int tid = threadIdx.x;
    long base = (long)blockIdx.x * CH;
    int n = (int)(((long)nE - base) < CH ? ((long)nE - base) : CH);
    if (n <= 0) return;

    for (int b = tid; b < nbuk; b += 256) hist[b] = 0;
    __syncthreads();
    for (int i = tid; i < n; i += 256)
        atomicAdd(&hist[((unsigned)dst[base + i]) >> BSHIFT], 1);
    __syncthreads();

    int b0 = tid * 4;
    int c0 = 0, c1 = 0, c2 = 0, c3 = 0, sum = 0;
    if (b0 < nbuk) {
        c0 = hist[b0];
        c1 = (b0 + 1 < nbuk) ? hist[b0 + 1] : 0;
        c2 = (b0 + 2 < nbuk) ? hist[b0 + 2] : 0;
        c3 = (b0 + 3 < nbuk) ? hist[b0 + 3] : 0;
        sum = c0 + c1 + c2 + c3;
    }
    int lane = tid & 63, wid = tid >> 6;
    int x = sum;
    #pragma unroll
    for (int off = 1; off < 64; off <<= 1) {
        int t = __shfl_up(x, off, 64);
        if (lane >= off) x += t;
    }
    if (lane == 63) wsum[wid] = x;
    __syncthreads();
    int wpre = 0;
    for (int w = 0; w < wid; ++w) wpre += wsum[w];
    int excl = wpre + x - sum;
    __syncthreads();
    if (b0 < nbuk) {
        int lb = excl;
        hist[b0] = lb;
        if (c0) { int g = atomicAdd(&gcur[b0], c0); dlt[b0] = g - lb; }
        lb += c0;
        if (b0 + 1 < nbuk) {
            hist[b0 + 1] = lb;
            if (c1) { int g = atomicAdd(&gcur[b0 + 1], c1); dlt[b0 + 1] = g - lb; }
            lb += c1;
        }
        if (b0 + 2 < nbuk) {
            hist[b0 + 2] = lb;
            if (c2) { int g = atomicAdd(&gcur[b0 + 2], c2); dlt[b0 + 2] = g - lb; }
            lb += c2;
        }
        if (b0 + 3 < nbuk) {
            hist[b0 + 3] = lb;
            if (c3) { int g = atomicAdd(&gcur[b0 + 3], c3); dlt[b0 + 3] = g - lb; }
        }
    }
    __syncthreads();

    for (int i = tid; i < n; i += 256) {
        unsigned d = (unsigned)dst[base + i];
        unsigned s = (unsigned)src[base + i];
        int slot = atomicAdd(&hist[d >> BSHIFT], 1);
        sk[slot] = d; sv[slot] = s;
    }
    __syncthreads();

    for (int i = tid; i < n; i += 256) {
        unsigned d = sk[i], s = sv[i];
        int b = (int)(d >> BSHIFT);
        long dest = (long)dlt[b] + i;
        long capend = (long)(b + 1) * BCAP;
        if (dest < capend) {
            part[dest] = ((d & (BNODES - 1)) << 24) | s;
        } else {
            int q = atomicAdd(ovf_cnt, 1);
            if (q < OVFD_CAP) ovf[q] = make_int2((int)d, (int)s);
        }
    }
}

// ---------------- partition: src keys only ----------------
__global__ __launch_bounds__(256)
void partition_keys_kernel(const int* __restrict__ key,
                           int* __restrict__ gcur,
                           unsigned* __restrict__ part,
                           int* __restrict__ spill_hist,  // odeg; spills add here
                           int nE, int nbuk) {
    __shared__ int hist[MAXBUK];
    __shared__ int dlt[MAXBUK];
    __shared__ int wsum[4];
    __shared__ unsigned sk[CH];

    int tid = threadIdx.x;
    long base = (long)blockIdx.x * CH;
    int n = (int)(((long)nE - base) < CH ? ((long)nE - base) : CH);
    if (n <= 0) return;

    for (int b = tid; b < nbuk; b += 256) hist[b] = 0;
    __syncthreads();
    for (int i = tid; i < n; i += 256)
        atomicAdd(&hist[((unsigned)key[base + i]) >> BSHIFT], 1);
    __syncthreads();

    int b0 = tid * 4;
    int c0 = 0, c1 = 0, c2 = 0, c3 = 0, sum = 0;
    if (b0 < nbuk) {
        c0 = hist[b0];
        c1 = (b0 + 1 < nbuk) ? hist[b0 + 1] : 0;
        c2 = (b0 + 2 < nbuk) ? hist[b0 + 2] : 0;
        c3 = (b0 + 3 < nbuk) ? hist[b0 + 3] : 0;
        sum = c0 + c1 + c2 + c3;
    }
    int lane = tid & 63, wid = tid >> 6;
    int x = sum;
    #pragma unroll
    for (int off = 1; off < 64; off <<= 1) {
        int t = __shfl_up(x, off, 64);
        if (lane >= off) x += t;
    }
    if (lane == 63) wsum[wid] = x;
    __syncthreads();
    int wpre = 0;
    for (int w = 0; w < wid; ++w) wpre += wsum[w];
    int excl = wpre + x - sum;
    __syncthreads();
    if (b0 < nbuk) {
        int lb = excl;
        hist[b0] = lb;
        if (c0) { int g = atomicAdd(&gcur[b0], c0); dlt[b0] = g - lb; }
        lb += c0;
        if (b0 + 1 < nbuk) {
            hist[b0 + 1] = lb;
            if (c1) { int g = atomicAdd(&gcur[b0 + 1], c1); dlt[b0 + 1] = g - lb; }
            lb += c1;
        }
        if (b0 + 2 < nbuk) {
            hist[b0 + 2] = lb;
            if (c2) { int g = atomicAdd(&gcur[b0 + 2], c2); dlt[b0 + 2] = g - lb; }
            lb += c2;
        }
        if (b0 + 3 < nbuk) {
            hist[b0 + 3] = lb;
            if (c3) { int g = atomicAdd(&gcur[b0 + 3], c3); dlt[b0 + 3] = g - lb; }
        }
    }
    __syncthreads();

    for (int i = tid; i < n; i += 256) {
        unsigned k = (unsigned)key[base + i];
        int slot = atomicAdd(&hist[k >> BSHIFT], 1);
        sk[slot] = k;
    }
    __syncthreads();

    for (int i = tid; i < n; i += 256) {
        unsigned k = sk[i];
        int b = (int)(k >> BSHIFT);
        long dest = (long)dlt[b] + i;
        long capend = (long)(b + 1) * BCAP;
        if (dest < capend) part[dest] = k;
        else atomicAdd(&spill_hist[k], 1);
    }
}

// ---------------- phase-2: odeg histogram ----------------
__global__ __launch_bounds__(256)
void odeg_phase2_kernel(const unsigned* __restrict__ part,
                        const int* __restrict__ gcur,
                        int* __restrict__ odeg, int nN) {
    __shared__ int bins[BNODES];
    int tid = threadIdx.x;
    int bucket = blockIdx.x;
    int nodeBase = bucket << BSHIFT;
    for (int b = tid; b < BNODES; b += 256) bins[b] = 0;
    __syncthreads();
    int start = bucket * BCAP;
    int endv = gcur[bucket];
    if (endv > start + BCAP) endv = start + BCAP;
    for (int i = start + tid; i < endv; i += 256)
        atomicAdd(&bins[(int)part[i] - nodeBase], 1);
    __syncthreads();
    for (int b = tid; b < BNODES; b += 256) {
        int node = nodeBase + b;
        if (node < nN && bins[b]) atomicAdd(&odeg[node], bins[b]);
    }
}

// ---------------- bf16 helpers ----------------
__device__ __forceinline__ unsigned short f2bf(float x) {
    unsigned u = __float_as_uint(x);
    u += 0x7fffu + ((u >> 16) & 1u);   // round-to-nearest-even
    return (unsigned short)(u >> 16);
}
__device__ __forceinline__ float bflo(unsigned u) { return __uint_as_float(u << 16); }
__device__ __forceinline__ float bfhi(unsigned u) { return __uint_as_float(u & 0xffff0000u); }

// ---------------- cast: sliced prescaled table ----------------
// tbl layout: [slice][node][16] bf16. One thread per float4 of the source row.
__global__ void cast_sliced_kernel(const float* __restrict__ u_f,
                                   const float* __restrict__ v_f,
                                   const int* __restrict__ odeg,
                                   unsigned short* __restrict__ tbl,
                                   int nN, int nU) {
    long i = (long)blockIdx.x * blockDim.x + threadIdx.x;
    long n4 = (long)nN * 32;
    if (i >= n4) return;
    int node = (int)(i >> 5);
    int q = (int)(i & 31);
    int slice = q >> 2, qi = q & 3;
    float norm = rsqrtf((float)max(odeg[node], 1));
    const float* base = (node < nU) ? (u_f + (size_t)node * DFEAT)
                                    : (v_f + (size_t)(node - nU) * DFEAT);
    float4 v = ((const float4*)base)[q];
    ushort4 o;
    o.x = f2bf(v.x * norm);
    o.y = f2bf(v.y * norm);
    o.z = f2bf(v.z * norm);
    o.w = f2bf(v.w * norm);
    ((ushort4*)tbl)[((size_t)slice * nN + node) * 4 + qi] = o;
}

// ---------------- aggregate: (bucket, slice) blocks ----------------
// slice = bid%8 -> pinned XCD (round-robin dispatch); 3.2MB slice table
// becomes L2-resident. LDS f32 accumulation, stride-17 padding.
#define ACC16(aptr, wA, wB)                                        \
    atomicAdd(&(aptr)[0],  bflo((wA).x)); atomicAdd(&(aptr)[1],  bfhi((wA).x)); \
    atomicAdd(&(aptr)[2],  bflo((wA).y)); atomicAdd(&(aptr)[3],  bfhi((wA).y)); \
    atomicAdd(&(aptr)[4],  bflo((wA).z)); atomicAdd(&(aptr)[5],  bfhi((wA).z)); \
    atomicAdd(&(aptr)[6],  bflo((wA).w)); atomicAdd(&(aptr)[7],  bfhi((wA).w)); \
    atomicAdd(&(aptr)[8],  bflo((wB).x)); atomicAdd(&(aptr)[9],  bfhi((wB).x)); \
    atomicAdd(&(aptr)[10], bflo((wB).y)); atomicAdd(&(aptr)[11], bfhi((wB).y)); \
    atomicAdd(&(aptr)[12], bflo((wB).z)); atomicAdd(&(aptr)[13], bfhi((wB).z)); \
    atomicAdd(&(aptr)[14], bflo((wB).w)); atomicAdd(&(aptr)[15], bfhi((wB).w))

__global__ __launch_bounds__(256)
void agg_sliced_kernel(const unsigned short* __restrict__ tbl,
                       const unsigned* __restrict__ part,
                       const int* __restrict__ gcur,
                       const int2* __restrict__ ovfD,
                       const int* __restrict__ ovfD_cnt,
                       float* __restrict__ out,
                       int nN) {
    __shared__ float accf[BNODES * 17];
    __shared__ int   cntl[BNODES];
    int tid = threadIdx.x;
    int slice  = blockIdx.x & (NSLICE - 1);
    int bucket = blockIdx.x >> 3;
    int nodeBase = bucket << BSHIFT;

    for (int i = tid; i < BNODES * 17; i += 256) accf[i] = 0.f;
    for (int i = tid; i < BNODES; i += 256) cntl[i] = 0;
    __syncthreads();

    const uint4* t4 = (const uint4*)(tbl + (size_t)slice * nN * SFEAT);

    int start = bucket * BCAP;
    int endv  = gcur[bucket];
    if (endv > start + BCAP) endv = start + BCAP;

    for (int i = start + tid; i < endv; i += 256) {
        unsigned p = part[i];
        int s  = (int)(p & 0xFFFFFFu);
        int dl = (int)(p >> 24);
        atomicAdd(&cntl[dl], 1);
        uint4 wA = t4[(size_t)s * 2 + 0];
        uint4 wB = t4[(size_t)s * 2 + 1];
        float* a = &accf[dl * 17];
        ACC16(a, wA, wB);
    }

    int m = *ovfD_cnt;                       // 0 in practice
    if (m > 0) {
        if (m > OVFD_CAP) m = OVFD_CAP;
        for (int j = tid; j < m; j += 256) {
            int d = ovfD[j].x, s = ovfD[j].y;
            if ((d >> BSHIFT) == bucket) {
                int dl = d & (BNODES - 1);
                atomicAdd(&cntl[dl], 1);
                uint4 wA = t4[(size_t)s * 2 + 0];
                uint4 wB = t4[(size_t)s * 2 + 1];
                float* a = &accf[dl * 17];
                ACC16(a, wA, wB);
            }
        }
    }
    __syncthreads();

    // writeback: 128 nodes x 4 float4 (64B per node, fused in-norm)
    for (int idx = tid; idx < BNODES * 4; idx += 256) {
        int nl = idx >> 2, q = idx & 3;
        int node = nodeBase + nl;
        if (node < nN) {
            float inorm = rsqrtf((float)max(cntl[nl], 1));
            const float* a = &accf[nl * 17 + q * 4];
            float4 v = make_float4(a[0] * inorm, a[1] * inorm,
                                   a[2] * inorm, a[3] * inorm);
            ((float4*)(out + (size_t)node * DFEAT + slice * SFEAT))[q] = v;
        }
    }
}

// ---------------- fallback: round-5 random-atomic build ----------------
__global__ void build_kernel(const int* __restrict__ src,
                             const int* __restrict__ dst,
                             int* __restrict__ ideg,
                             int* __restrict__ odeg,
                             int* __restrict__ slack,
                             int2* __restrict__ ovf2,
                             int* __restrict__ ovf2_cnt,
                             int nE) {
    int t = blockIdx.x * blockDim.x + threadIdx.x;
    long base = (long)t * 4;
    if (base >= nE) return;
    long lim = base + 4 < (long)nE ? base + 4 : (long)nE;
    for (long e = base; e < lim; ++e) {
        int s = src[e], d = dst[e];
        atomicAdd(&odeg[s], 1);
        int p = atomicAdd(&ideg[d], 1);
        if (p < SLACK) {
            slack[(size_t)d * SLACK + p] = s;
        } else {
            int q = atomicAdd(ovf2_cnt, 1);
            if (q < OVF2_CAP) ovf2[q] = make_int2(d, s);
        }
    }
}

__launch_bounds__(256)
__global__ void aggregate_f32_kernel(const float* __restrict__ u_f,
                                     const float* __restrict__ v_f,
                                     const int* __restrict__ slack,
                                     const int* __restrict__ ideg,
                                     const int* __restrict__ odeg,
                                     const int2* __restrict__ ovf2,
                                     const int* __restrict__ ovf2_cnt,
                                     float* __restrict__ out,
                                     int nN, int nU) {
    int lane = threadIdx.x & 63;
    int wid  = threadIdx.x >> 6;
    int node = blockIdx.x * 4 + wid;
    if (node >= nN) return;

    int deg = ideg[node];
    int cnt = min(deg, SLACK);
    int   sb = 0;
    float nb = 0.f;
    if (lane < cnt) {
        sb = slack[(size_t)node * SLACK + lane];
        nb = rsqrtf((float)max(odeg[sb], 1));
    }
    float2 acc = make_float2(0.f, 0.f);
    for (int k = 0; k < cnt; ++k) {
        int   sk = __shfl(sb, k, 64);
        float nk = __shfl(nb, k, 64);
        const float* row = (sk < nU) ? (u_f + (size_t)sk * DFEAT)
                                     : (v_f + (size_t)(sk - nU) * DFEAT);
        float2 v = ((const float2*)row)[lane];
        acc.x += v.x * nk;
        acc.y += v.y * nk;
    }
    if (deg > SLACK) {
        int m = *ovf2_cnt; if (m > OVF2_CAP) m = OVF2_CAP;
        for (int j = 0; j < m; ++j) {
            int2 os = ovf2[j];
            if (os.x == node) {
                int sk = os.y;
                float nk = rsqrtf((float)max(odeg[sk], 1));
                const float* row = (sk < nU) ? (u_f + (size_t)sk * DFEAT)
                                             : (v_f + (size_t)(sk - nU) * DFEAT);
                float2 v = ((const float2*)row)[lane];
                acc.x += v.x * nk;
                acc.y += v.y * nk;
            }
        }
    }
    float inorm = rsqrtf((float)max(deg, 1));
    acc.x *= inorm; acc.y *= inorm;
    ((float2*)(out + (size_t)node * DFEAT))[lane] = acc;
}

extern "C" void kernel_launch(void* const* d_in, const int* in_sizes, int n_in,
                              void* d_out, int out_size, void* d_ws, size_t ws_size,
                              hipStream_t stream) {
    const float* u_f = (const float*)d_in[0];
    const float* v_f = (const float*)d_in[1];
    const int*   src = (const int*)d_in[2];
    const int*   dst = (const int*)d_in[3];
    float* out = (float*)d_out;

    int nU = in_sizes[0] / DFEAT;
    int nV = in_sizes[1] / DFEAT;
    int nN = nU + nV;
    int nE = in_sizes[2];
    int nbuk = (nN + BNODES - 1) >> BSHIFT;

    // ---- new-path workspace layout (ints) ----
    int*  odeg  = (int*)d_ws;
    int*  cnts  = odeg + nN;                 // [1] = ovfD_cnt
    int2* ovfD  = (int2*)(cnts + 8);
    int*  gcurD = (int*)(ovfD + OVFD_CAP);
    int*  gcurS = gcurD + MAXBUK;
    unsigned* partD = (unsigned*)(gcurS + MAXBUK);
    unsigned* partS = partD + (size_t)nbuk * BCAP;
    unsigned short* tbl = (unsigned short*)partS;   // overlays partS (dead by cast)
    size_t partInts  = (size_t)nbuk * BCAP;
    size_t tblInts   = (size_t)nN * (DFEAT / 2);
    size_t unionInts = partInts > tblInts ? partInts : tblInts;
    size_t needNew = ((size_t)nN + 8 + 2 * (size_t)OVFD_CAP + 2 * MAXBUK
                      + partInts + unionInts) * 4;
    bool use_new = (nN <= (MAXBUK << BSHIFT)) && (nN < (1 << 24))
                   && (ws_size >= needNew);

    if (use_new) {
        hipMemsetAsync(d_ws, 0, ((size_t)nN + 8) * sizeof(int), stream);
        int nCh = (nE + CH - 1) / CH;
        init_kernel<<<(nbuk + 255) / 256, 256, 0, stream>>>(gcurD, gcurS, nbuk);
        partition_keys_kernel<<<nCh, 256, 0, stream>>>(src, gcurS, partS, odeg,
                                                       nE, nbuk);
        odeg_phase2_kernel<<<nbuk, 256, 0, stream>>>(partS, gcurS, odeg, nN);
        partition_pairs_kernel<<<nCh, 256, 0, stream>>>(dst, src, gcurD, partD,
                                                        ovfD, cnts + 1, nE, nbuk);
        {
            long n4 = (long)nN * 32;
            cast_sliced_kernel<<<(int)((n4 + 255) / 256), 256, 0, stream>>>(
                u_f, v_f, odeg, tbl, nN, nU);
        }
        agg_sliced_kernel<<<nbuk * NSLICE, 256, 0, stream>>>(tbl, partD, gcurD,
                                                             ovfD, cnts + 1,
                                                             out, nN);
    } else {
        // ---- fallback: round-5 layout ----
        int*  f_ideg = (int*)d_ws;
        int*  f_odeg = f_ideg + nN;
        int*  f_cnts = f_odeg + nN;          // [0] = ovf2_cnt
        int2* f_ovf2 = (int2*)(f_cnts + 8);
        int*  f_slack = (int*)(f_ovf2 + OVF2_CAP);

        hipMemsetAsync(d_ws, 0, ((size_t)2 * nN + 8) * sizeof(int), stream);
        long nT = ((long)nE + 3) / 4;
        build_kernel<<<(int)((nT + 255) / 256), 256, 0, stream>>>(
            src, dst, f_ideg, f_odeg, f_slack, f_ovf2, f_cnts + 0, nE);
        aggregate_f32_kernel<<<(nN + 3) / 4, 256, 0, stream>>>(
            u_f, v_f, f_slack, f_ideg, f_odeg, f_ovf2, f_cnts + 0, out, nN, nU);
    }
}

// Round 8
// 333.444 us; speedup vs baseline: 3.5064x; 3.5064x over previous
//
#include <hip/hip_runtime.h>

// GCN aggregation — bucketed partition + feature-sliced XCD-pinned gather,
// register-accumulation aggregate (round-7 data path, round-6 execution style).
//   out = diag(in_deg^-1/2) * A * diag(out_deg^-1/2) * concat(u_f, v_f)
//
// Pipeline:
//   init : gcurD[b]=gcurS[b]=b*BCAP
//   P1s  : partition src keys into 128-node buckets (LDS staged)
//   P2s  : per-bucket LDS histogram -> odeg
//   P1d  : partition edges by dst bucket, PACKED (d_local<<24|src) uint
//   cast : sliced bf16 table  tbl[slice][node][16] = bf16(node_f * rsqrt(odeg))
//   agg  : block=(bucket,slice); slice=bid&7 -> pinned XCD (3.2MB slice table
//          L2-resident, proven R7: FETCH 60MB). Per block: LDS slot-binning of
//          packed pairs, then wave-per-node register accum (8 lanes/row),
//          shfl reduce, fused in-norm, 64B stores.
//
// Fallback (small ws): round-5 slack-CSR random-atomic build + f32 gather.

#define DFEAT 128
#define SLACK 64
#define OVF2_CAP 65536
#define OVFD_CAP 65536
#define BSHIFT 7
#define BNODES 128
#define MAXBUK 1024         // supports nN <= 131072
#define BCAP 4096
#define CH 6144
#define NSLICE 8
#define SFEAT 16            // features per slice
#define SLOTCAP 64          // LDS slots per node in agg binning
#define SLOTSTRIDE 65       // +1 pad: bank = (nl + slot) % 32

// ---------------- init ----------------
__global__ void init_kernel(int* __restrict__ gcurD, int* __restrict__ gcurS,
                            int nbuk) {
    int b = blockIdx.x * blockDim.x + threadIdx.x;
    if (b < nbuk) { gcurD[b] = b * BCAP; gcurS[b] = b * BCAP; }
}

// ---------------- partition: (dst,src) pairs, packed flush ----------------
__global__ __launch_bounds__(256)
void partition_pairs_kernel(const int* __restrict__ dst,
                            const int* __restrict__ src,
                            int* __restrict__ gcur,
                            unsigned* __restrict__ part,   // packed uint
                            int2* __restrict__ ovf,
                            int* __restrict__ ovf_cnt,
                            int nE, int nbuk) {
    __shared__ int hist[MAXBUK];
    __shared__ int dlt[MAXBUK];
    __shared__ int wsum[4];
    __shared__ unsigned sk[CH];
    __shared__ unsigned sv[CH];

    int tid = threadIdx.x;
    long base = (long)blockIdx.x * CH;
    int n = (int)(((long)nE - base) < CH ? ((long)nE - base) : CH);
    if (n <= 0) return;

    for (int b = tid; b < nbuk; b += 256) hist[b] = 0;
    __syncthreads();
    for (int i = tid; i < n; i += 256)
        atomicAdd(&hist[((unsigned)dst[base + i]) >> BSHIFT], 1);
    __syncthreads();

    int b0 = tid * 4;
    int c0 = 0, c1 = 0, c2 = 0, c3 = 0, sum = 0;
    if (b0 < nbuk) {
        c0 = hist[b0];
        c1 = (b0 + 1 < nbuk) ? hist[b0 + 1] : 0;
        c2 = (b0 + 2 < nbuk) ? hist[b0 + 2] : 0;
        c3 = (b0 + 3 < nbuk) ? hist[b0 + 3] : 0;
        sum = c0 + c1 + c2 + c3;
    }
    int lane = tid & 63, wid = tid >> 6;
    int x = sum;
    #pragma unroll
    for (int off = 1; off < 64; off <<= 1) {
        int t = __shfl_up(x, off, 64);
        if (lane >= off) x += t;
    }
    if (lane == 63) wsum[wid] = x;
    __syncthreads();
    int wpre = 0;
    for (int w = 0; w < wid; ++w) wpre += wsum[w];
    int excl = wpre + x - sum;
    __syncthreads();
    if (b0 < nbuk) {
        int lb = excl;
        hist[b0] = lb;
        if (c0) { int g = atomicAdd(&gcur[b0], c0); dlt[b0] = g - lb; }
        lb += c0;
        if (b0 + 1 < nbuk) {
            hist[b0 + 1] = lb;
            if (c1) { int g = atomicAdd(&gcur[b0 + 1], c1); dlt[b0 + 1] = g - lb; }
            lb += c1;
        }
        if (b0 + 2 < nbuk) {
            hist[b0 + 2] = lb;
            if (c2) { int g = atomicAdd(&gcur[b0 + 2], c2); dlt[b0 + 2] = g - lb; }
            lb += c2;
        }
        if (b0 + 3 < nbuk) {
            hist[b0 + 3] = lb;
            if (c3) { int g = atomicAdd(&gcur[b0 + 3], c3); dlt[b0 + 3] = g - lb; }
        }
    }
    __syncthreads();

    for (int i = tid; i < n; i += 256) {
        unsigned d = (unsigned)dst[base + i];
        unsigned s = (unsigned)src[base + i];
        int slot = atomicAdd(&hist[d >> BSHIFT], 1);
        sk[slot] = d; sv[slot] = s;
    }
    __syncthreads();

    for (int i = tid; i < n; i += 256) {
        unsigned d = sk[i], s = sv[i];
        int b = (int)(d >> BSHIFT);
        long dest = (long)dlt[b] + i;
        long capend = (long)(b + 1) * BCAP;
        if (dest < capend) {
            part[dest] = ((d & (BNODES - 1)) << 24) | s;
        } else {
            int q = atomicAdd(ovf_cnt, 1);
            if (q < OVFD_CAP) ovf[q] = make_int2((int)d, (int)s);
        }
    }
}

// ---------------- partition: src keys only ----------------
__global__ __launch_bounds__(256)
void partition_keys_kernel(const int* __restrict__ key,
                           int* __restrict__ gcur,
                           unsigned* __restrict__ part,
                           int* __restrict__ spill_hist,  // odeg; spills add here
                           int nE, int nbuk) {
    __shared__ int hist[MAXBUK];
    __shared__ int dlt[MAXBUK];
    __shared__ int wsum[4];
    __shared__ unsigned sk[CH];

    int tid = threadIdx.x;
    long base = (long)blockIdx.x * CH;
    int n = (int)(((long)nE - base) < CH ? ((long)nE - base) : CH);
    if (n <= 0) return;

    for (int b = tid; b < nbuk; b += 256) hist[b] = 0;
    __syncthreads();
    for (int i = tid; i < n; i += 256)
        atomicAdd(&hist[((unsigned)key[base + i]) >> BSHIFT], 1);
    __syncthreads();

    int b0 = tid * 4;
    int c0 = 0, c1 = 0, c2 = 0, c3 = 0, sum = 0;
    if (b0 < nbuk) {
        c0 = hist[b0];
        c1 = (b0 + 1 < nbuk) ? hist[b0 + 1] : 0;
        c2 = (b0 + 2 < nbuk) ? hist[b0 + 2] : 0;
        c3 = (b0 + 3 < nbuk) ? hist[b0 + 3] : 0;
        sum = c0 + c1 + c2 + c3;
    }
    int lane = tid & 63, wid = tid >> 6;
    int x = sum;
    #pragma unroll
    for (int off = 1; off < 64; off <<= 1) {
        int t = __shfl_up(x, off, 64);
        if (lane >= off) x += t;
    }
    if (lane == 63) wsum[wid] = x;
    __syncthreads();
    int wpre = 0;
    for (int w = 0; w < wid; ++w) wpre += wsum[w];
    int excl = wpre + x - sum;
    __syncthreads();
    if (b0 < nbuk) {
        int lb = excl;
        hist[b0] = lb;
        if (c0) { int g = atomicAdd(&gcur[b0], c0); dlt[b0] = g - lb; }
        lb += c0;
        if (b0 + 1 < nbuk) {
            hist[b0 + 1] = lb;
            if (c1) { int g = atomicAdd(&gcur[b0 + 1], c1); dlt[b0 + 1] = g - lb; }
            lb += c1;
        }
        if (b0 + 2 < nbuk) {
            hist[b0 + 2] = lb;
            if (c2) { int g = atomicAdd(&gcur[b0 + 2], c2); dlt[b0 + 2] = g - lb; }
            lb += c2;
        }
        if (b0 + 3 < nbuk) {
            hist[b0 + 3] = lb;
            if (c3) { int g = atomicAdd(&gcur[b0 + 3], c3); dlt[b0 + 3] = g - lb; }
        }
    }
    __syncthreads();

    for (int i = tid; i < n; i += 256) {
        unsigned k = (unsigned)key[base + i];
        int slot = atomicAdd(&hist[k >> BSHIFT], 1);
        sk[slot] = k;
    }
    __syncthreads();

    for (int i = tid; i < n; i += 256) {
        unsigned k = sk[i];
        int b = (int)(k >> BSHIFT);
        long dest = (long)dlt[b] + i;
        long capend = (long)(b + 1) * BCAP;
        if (dest < capend) part[dest] = k;
        else atomicAdd(&spill_hist[k], 1);
    }
}

// ---------------- phase-2: odeg histogram ----------------
__global__ __launch_bounds__(256)
void odeg_phase2_kernel(const unsigned* __restrict__ part,
                        const int* __restrict__ gcur,
                        int* __restrict__ odeg, int nN) {
    __shared__ int bins[BNODES];
    int tid = threadIdx.x;
    int bucket = blockIdx.x;
    int nodeBase = bucket << BSHIFT;
    for (int b = tid; b < BNODES; b += 256) bins[b] = 0;
    __syncthreads();
    int start = bucket * BCAP;
    int endv = gcur[bucket];
    if (endv > start + BCAP) endv = start + BCAP;
    for (int i = start + tid; i < endv; i += 256)
        atomicAdd(&bins[(int)part[i] - nodeBase], 1);
    __syncthreads();
    for (int b = tid; b < BNODES; b += 256) {
        int node = nodeBase + b;
        if (node < nN && bins[b]) atomicAdd(&odeg[node], bins[b]);
    }
}

// ---------------- bf16 helpers ----------------
__device__ __forceinline__ unsigned short f2bf(float x) {
    unsigned u = __float_as_uint(x);
    u += 0x7fffu + ((u >> 16) & 1u);   // round-to-nearest-even
    return (unsigned short)(u >> 16);
}
__device__ __forceinline__ float bflo(unsigned u) { return __uint_as_float(u << 16); }
__device__ __forceinline__ float bfhi(unsigned u) { return __uint_as_float(u & 0xffff0000u); }

// ---------------- cast: sliced prescaled table ----------------
// tbl layout: [slice][node][16] bf16. One thread per float4 of the source row.
__global__ void cast_sliced_kernel(const float* __restrict__ u_f,
                                   const float* __restrict__ v_f,
                                   const int* __restrict__ odeg,
                                   unsigned short* __restrict__ tbl,
                                   int nN, int nU) {
    long i = (long)blockIdx.x * blockDim.x + threadIdx.x;
    long n4 = (long)nN * 32;
    if (i >= n4) return;
    int node = (int)(i >> 5);
    int q = (int)(i & 31);
    int slice = q >> 2, qi = q & 3;
    float norm = rsqrtf((float)max(odeg[node], 1));
    const float* base = (node < nU) ? (u_f + (size_t)node * DFEAT)
                                    : (v_f + (size_t)(node - nU) * DFEAT);
    float4 v = ((const float4*)base)[q];
    ushort4 o;
    o.x = f2bf(v.x * norm);
    o.y = f2bf(v.y * norm);
    o.z = f2bf(v.z * norm);
    o.w = f2bf(v.w * norm);
    ((ushort4*)tbl)[((size_t)slice * nN + node) * 4 + qi] = o;
}

// ---------------- aggregate: (bucket, slice) blocks, register accum ----------
// slice = bid&7 -> pinned XCD; slice table (nN*32B ~ 3.2MB) L2-resident.
// Phase A: bin packed pairs into LDS slots (int atomics, stride-65 pad).
// Phase B: wave-per-node, 8 lanes per row (1 uint = 2 bf16 each), shfl reduce.
__global__ __launch_bounds__(256)
void agg_sliced2_kernel(const unsigned short* __restrict__ tbl,
                        const unsigned* __restrict__ part,
                        const int* __restrict__ gcur,
                        const int2* __restrict__ ovfD,
                        const int* __restrict__ ovfD_cnt,
                        float* __restrict__ out,
                        int nN) {
    __shared__ unsigned sl[BNODES * SLOTSTRIDE];
    __shared__ int cnt[BNODES];
    int tid = threadIdx.x;
    int slice  = blockIdx.x & (NSLICE - 1);
    int bucket = blockIdx.x >> 3;
    int nodeBase = bucket << BSHIFT;

    for (int i = tid; i < BNODES; i += 256) cnt[i] = 0;
    __syncthreads();

    int start = bucket * BCAP;
    int endv  = gcur[bucket];
    if (endv > start + BCAP) endv = start + BCAP;

    // Phase A: bin into LDS slots
    for (int i = start + tid; i < endv; i += 256) {
        unsigned p = part[i];
        int dl = (int)(p >> 24);
        int slot = atomicAdd(&cnt[dl], 1);
        if (slot < SLOTCAP) sl[dl * SLOTSTRIDE + slot] = p;
    }
    __syncthreads();

    // Phase B: wave per node
    int lane = tid & 63;
    int wid  = tid >> 6;
    int eg   = lane >> 3;    // entry group 0..7
    int sub  = lane & 7;     // uint index within 16-feat row

    const unsigned* t4u = (const unsigned*)(tbl + (size_t)slice * nN * SFEAT);
    int m = *ovfD_cnt;                       // 0 in practice
    if (m > OVFD_CAP) m = OVFD_CAP;

    for (int nl = wid; nl < BNODES; nl += 4) {
        int deg = cnt[nl];
        float a0 = 0.f, a1 = 0.f;
        int extra = 0;

        if (deg <= SLOTCAP) {
            for (int e = eg; e < deg; e += 8) {
                unsigned s = sl[nl * SLOTSTRIDE + e] & 0xFFFFFFu;
                unsigned w = t4u[(size_t)s * 8 + sub];
                a0 += bflo(w); a1 += bfhi(w);
            }
        } else {
            // rare: rescan full bucket list for this node
            for (int i = start + eg; i < endv; i += 8) {
                unsigned p = part[i];
                if ((int)(p >> 24) == nl) {
                    unsigned w = t4u[(size_t)(p & 0xFFFFFFu) * 8 + sub];
                    a0 += bflo(w); a1 += bfhi(w);
                }
            }
        }
        if (m > 0) {
            // rare: global partition spill entries for this bucket/node
            int node = nodeBase + nl;
            for (int j = eg; j < m; j += 8) {
                int2 e = ovfD[j];
                if (e.x == node) {
                    unsigned w = t4u[(size_t)e.y * 8 + sub];
                    a0 += bflo(w); a1 += bfhi(w);
                    ++extra;
                }
            }
        }

        a0 += __shfl_xor(a0, 8, 64);  a1 += __shfl_xor(a1, 8, 64);
        a0 += __shfl_xor(a0, 16, 64); a1 += __shfl_xor(a1, 16, 64);
        a0 += __shfl_xor(a0, 32, 64); a1 += __shfl_xor(a1, 32, 64);
        if (m > 0) {
            extra += __shfl_xor(extra, 8, 64);
            extra += __shfl_xor(extra, 16, 64);
            extra += __shfl_xor(extra, 32, 64);
        }

        int node = nodeBase + nl;
        if (node < nN && lane < 8) {
            float inorm = rsqrtf((float)max(deg + extra, 1));
            ((float2*)(out + (size_t)node * DFEAT + slice * SFEAT))[lane] =
                make_float2(a0 * inorm, a1 * inorm);
        }
    }
}

// ---------------- fallback: round-5 random-atomic build ----------------
__global__ void build_kernel(const int* __restrict__ src,
                             const int* __restrict__ dst,
                             int* __restrict__ ideg,
                             int* __restrict__ odeg,
                             int* __restrict__ slack,
                             int2* __restrict__ ovf2,
                             int* __restrict__ ovf2_cnt,
                             int nE) {
    int t = blockIdx.x * blockDim.x + threadIdx.x;
    long base = (long)t * 4;
    if (base >= nE) return;
    long lim = base + 4 < (long)nE ? base + 4 : (long)nE;
    for (long e = base; e < lim; ++e) {
        int s = src[e], d = dst[e];
        atomicAdd(&odeg[s], 1);
        int p = atomicAdd(&ideg[d], 1);
        if (p < SLACK) {
            slack[(size_t)d * SLACK + p] = s;
        } else {
            int q = atomicAdd(ovf2_cnt, 1);
            if (q < OVF2_CAP) ovf2[q] = make_int2(d, s);
        }
    }
}

__launch_bounds__(256)
__global__ void aggregate_f32_kernel(const float* __restrict__ u_f,
                                     const float* __restrict__ v_f,
                                     const int* __restrict__ slack,
                                     const int* __restrict__ ideg,
                                     const int* __restrict__ odeg,
                                     const int2* __restrict__ ovf2,
                                     const int* __restrict__ ovf2_cnt,
                                     float* __restrict__ out,
                                     int nN, int nU) {
    int lane = threadIdx.x & 63;
    int wid  = threadIdx.x >> 6;
    int node = blockIdx.x * 4 + wid;
    if (node >= nN) return;

    int deg = ideg[node];
    int cnt = min(deg, SLACK);
    int   sb = 0;
    float nb = 0.f;
    if (lane < cnt) {
        sb = slack[(size_t)node * SLACK + lane];
        nb = rsqrtf((float)max(odeg[sb], 1));
    }
    float2 acc = make_float2(0.f, 0.f);
    for (int k = 0; k < cnt; ++k) {
        int   sk = __shfl(sb, k, 64);
        float nk = __shfl(nb, k, 64);
        const float* row = (sk < nU) ? (u_f + (size_t)sk * DFEAT)
                                     : (v_f + (size_t)(sk - nU) * DFEAT);
        float2 v = ((const float2*)row)[lane];
        acc.x += v.x * nk;
        acc.y += v.y * nk;
    }
    if (deg > SLACK) {
        int m = *ovf2_cnt; if (m > OVF2_CAP) m = OVF2_CAP;
        for (int j = 0; j < m; ++j) {
            int2 os = ovf2[j];
            if (os.x == node) {
                int sk = os.y;
                float nk = rsqrtf((float)max(odeg[sk], 1));
                const float* row = (sk < nU) ? (u_f + (size_t)sk * DFEAT)
                                             : (v_f + (size_t)(sk - nU) * DFEAT);
                float2 v = ((const float2*)row)[lane];
                acc.x += v.x * nk;
                acc.y += v.y * nk;
            }
        }
    }
    float inorm = rsqrtf((float)max(deg, 1));
    acc.x *= inorm; acc.y *= inorm;
    ((float2*)(out + (size_t)node * DFEAT))[lane] = acc;
}

extern "C" void kernel_launch(void* const* d_in, const int* in_sizes, int n_in,
                              void* d_out, int out_size, void* d_ws, size_t ws_size,
                              hipStream_t stream) {
    const float* u_f = (const float*)d_in[0];
    const float* v_f = (const float*)d_in[1];
    const int*   src = (const int*)d_in[2];
    const int*   dst = (const int*)d_in[3];
    float* out = (float*)d_out;

    int nU = in_sizes[0] / DFEAT;
    int nV = in_sizes[1] / DFEAT;
    int nN = nU + nV;
    int nE = in_sizes[2];
    int nbuk = (nN + BNODES - 1) >> BSHIFT;

    // ---- new-path workspace layout (ints) ----
    int*  odeg  = (int*)d_ws;
    int*  cnts  = odeg + nN;                 // [1] = ovfD_cnt
    int2* ovfD  = (int2*)(cnts + 8);
    int*  gcurD = (int*)(ovfD + OVFD_CAP);
    int*  gcurS = gcurD + MAXBUK;
    unsigned* partD = (unsigned*)(gcurS + MAXBUK);
    unsigned* partS = partD + (size_t)nbuk * BCAP;
    unsigned short* tbl = (unsigned short*)partS;   // overlays partS (dead by cast)
    size_t partInts  = (size_t)nbuk * BCAP;
    size_t tblInts   = (size_t)nN * (DFEAT / 2);
    size_t unionInts = partInts > tblInts ? partInts : tblInts;
    size_t needNew = ((size_t)nN + 8 + 2 * (size_t)OVFD_CAP + 2 * MAXBUK
                      + partInts + unionInts) * 4;
    bool use_new = (nN <= (MAXBUK << BSHIFT)) && (nN < (1 << 24))
                   && (ws_size >= needNew);

    if (use_new) {
        hipMemsetAsync(d_ws, 0, ((size_t)nN + 8) * sizeof(int), stream);
        int nCh = (nE + CH - 1) / CH;
        init_kernel<<<(nbuk + 255) / 256, 256, 0, stream>>>(gcurD, gcurS, nbuk);
        partition_keys_kernel<<<nCh, 256, 0, stream>>>(src, gcurS, partS, odeg,
                                                       nE, nbuk);
        odeg_phase2_kernel<<<nbuk, 256, 0, stream>>>(partS, gcurS, odeg, nN);
        partition_pairs_kernel<<<nCh, 256, 0, stream>>>(dst, src, gcurD, partD,
                                                        ovfD, cnts + 1, nE, nbuk);
        {
            long n4 = (long)nN * 32;
            cast_sliced_kernel<<<(int)((n4 + 255) / 256), 256, 0, stream>>>(
                u_f, v_f, odeg, tbl, nN, nU);
        }
        agg_sliced2_kernel<<<nbuk * NSLICE, 256, 0, stream>>>(tbl, partD, gcurD,
                                                              ovfD, cnts + 1,
                                                              out, nN);
    } else {
        // ---- fallback: round-5 layout ----
        int*  f_ideg = (int*)d_ws;
        int*  f_odeg = f_ideg + nN;
        int*  f_cnts = f_odeg + nN;          // [0] = ovf2_cnt
        int2* f_ovf2 = (int2*)(f_cnts + 8);
        int*  f_slack = (int*)(f_ovf2 + OVF2_CAP);

        hipMemsetAsync(d_ws, 0, ((size_t)2 * nN + 8) * sizeof(int), stream);
        long nT = ((long)nE + 3) / 4;
        build_kernel<<<(int)((nT + 255) / 256), 256, 0, stream>>>(
            src, dst, f_ideg, f_odeg, f_slack, f_ovf2, f_cnts + 0, nE);
        aggregate_f32_kernel<<<(nN + 3) / 4, 256, 0, stream>>>(
            u_f, v_f, f_slack, f_ideg, f_odeg, f_ovf2, f_cnts + 0, out, nN, nU);
    }
}